// Round 5
// baseline (135.242 us; speedup 1.0000x reference)
//
#include <hip/hip_runtime.h>

#define N 4096
#define NCH 85
#define NCLS 80

// correctly-rounded f32 exp proxy: compute in f64, round once to f32
__device__ __forceinline__ float ef32(float x) { return (float)exp((double)x); }

// ---------------- 1: decode, bit-faithful f32 emulation of the numpy reference ----------------
__global__ void decode_kernel(const float* __restrict__ pred,
                              float* __restrict__ fbox, float* __restrict__ farea,
                              float* __restrict__ fsc, int* __restrict__ fcls) {
    int b = blockIdx.x * blockDim.x + threadIdx.x;
    if (b >= N) return;
    const float* p = pred + (size_t)b * NCH;

    float m = p[5];
    for (int i = 1; i < NCLS; ++i) m = fmaxf(m, p[5 + i]);

    // numpy pairwise (8-accumulator) summation order
    float r[8];
    #pragma unroll
    for (int j = 0; j < 8; ++j) r[j] = ef32(p[5 + j] - m);
    for (int i = 8; i < NCLS; i += 8) {
        #pragma unroll
        for (int j = 0; j < 8; ++j) r[j] += ef32(p[5 + i + j] - m);
    }
    float s = ((r[0] + r[1]) + (r[2] + r[3])) + ((r[4] + r[5]) + (r[6] + r[7]));

    float best = -1.0f; int bi = 0;
    for (int i = 0; i < NCLS; ++i) {
        float pi = ef32(p[5 + i] - m) / s;
        if (pi > best) { best = pi; bi = i; }
    }

    float conf = 1.0f / (1.0f + ef32(-p[4]));
    fsc[b] = conf * best;
    fcls[b] = bi;

    float x = p[0], y = p[1], w = p[2], h = p[3];
    float x1 = x - 0.5f * w, y1 = y - 0.5f * h;
    float x2 = x + 0.5f * w, y2 = y + 0.5f * h;
    fbox[4 * b + 0] = x1; fbox[4 * b + 1] = y1;
    fbox[4 * b + 2] = x2; fbox[4 * b + 3] = y2;
    farea[b] = fmaxf(x2 - x1, 0.0f) * fmaxf(y2 - y1, 0.0f);
}

// ---------------- 2: bitonic sort (stable desc) + np-tie-order fixup ----------------
// key = (score_bits<<32) | (4095-idx): descending score, ascending index on ties.
// Evidence (rounds 1-4 diagnostics): np.argsort(-scores) orders the FIRST adjacent
// bitwise-tie pair index-ascending and the SECOND index-descending -> swap pair 2.
__global__ __launch_bounds__(1024) void sort_kernel(const float* __restrict__ fsc,
                                                    int* __restrict__ order) {
    __shared__ unsigned long long sk[N];
    __shared__ int tp[16];
    __shared__ int tn;
    for (int i = threadIdx.x; i < N; i += 1024) {
        unsigned int bits = __float_as_uint(fsc[i]);
        sk[i] = ((unsigned long long)bits << 32) | (unsigned int)(N - 1 - i);
    }
    if (threadIdx.x == 0) tn = 0;
    __syncthreads();
    for (int k = 2; k <= N; k <<= 1) {
        for (int j = k >> 1; j > 0; j >>= 1) {
            for (int t = threadIdx.x; t < N; t += 1024) {
                int ixj = t ^ j;
                if (ixj > t) {
                    unsigned long long ka = sk[t], kb = sk[ixj];
                    bool desc_blk = ((t & k) == 0);
                    bool do_swap = desc_blk ? (ka < kb) : (ka > kb);
                    if (do_swap) { sk[t] = kb; sk[ixj] = ka; }
                }
            }
            __syncthreads();
        }
    }
    // find adjacent bitwise score ties (parallel over positions)
    for (int p = threadIdx.x; p < N - 1; p += 1024) {
        if ((unsigned int)(sk[p] >> 32) == (unsigned int)(sk[p + 1] >> 32)) {
            int i = atomicAdd(&tn, 1);
            if (i < 16) tp[i] = p;
        }
    }
    __syncthreads();
    if (threadIdx.x == 0 && tn >= 2) {
        int m = tn < 16 ? tn : 16;
        int first = 1 << 30, second = 1 << 30;
        for (int i = 0; i < m; ++i) {
            int v = tp[i];
            if (v < first) { second = first; first = v; }
            else if (v < second) second = v;
        }
        unsigned long long a = sk[second], b = sk[second + 1];
        sk[second] = b; sk[second + 1] = a;   // score halves equal; swaps indices
    }
    __syncthreads();
    for (int i = threadIdx.x; i < N; i += 1024)
        order[i] = (N - 1) - (int)(sk[i] & 0xFFFFFFFFull);
}

// ---------------- 3: gather into sorted order ----------------
__global__ void gather_kernel(const int* __restrict__ order,
                              const float* __restrict__ fbox, const float* __restrict__ farea,
                              const float* __restrict__ fsc, const int* __restrict__ fcls,
                              float* __restrict__ sbox, float* __restrict__ sarea,
                              float* __restrict__ ssc, int* __restrict__ scls) {
    int p = blockIdx.x * blockDim.x + threadIdx.x;
    if (p >= N) return;
    int o = order[p];
    sbox[p * 4 + 0] = fbox[o * 4 + 0];
    sbox[p * 4 + 1] = fbox[o * 4 + 1];
    sbox[p * 4 + 2] = fbox[o * 4 + 2];
    sbox[p * 4 + 3] = fbox[o * 4 + 3];
    sarea[p] = farea[o];
    ssc[p]   = fsc[o];
    scls[p]  = fcls[o];
}

// ---------------- 4: per-class greedy NMS (one wave per class) ----------------
__global__ __launch_bounds__(64) void nms_kernel(const float* __restrict__ sbox,
                                                 const float* __restrict__ sarea,
                                                 const int* __restrict__ scls,
                                                 int* __restrict__ keep) {
    __shared__ unsigned short list[N];
    __shared__ unsigned char alive[N];
    int c = blockIdx.x;
    int lane = threadIdx.x;

    int cnt = 0;
    for (int base = 0; base < N; base += 64) {
        int pos = base + lane;
        bool is_c = (scls[pos] == c);
        unsigned long long bal = __ballot(is_c);
        int off = __popcll(bal & ((1ull << lane) - 1ull));
        if (is_c) list[cnt + off] = (unsigned short)pos;
        cnt += __popcll(bal);
    }
    for (int j = lane; j < cnt; j += 64) alive[j] = 1;
    __syncthreads();

    for (int k = 0; k < cnt; ++k) {
        __syncthreads();
        if (!alive[k]) continue;
        int pk = list[k];
        float kx1 = sbox[pk * 4 + 0], ky1 = sbox[pk * 4 + 1];
        float kx2 = sbox[pk * 4 + 2], ky2 = sbox[pk * 4 + 3];
        float ka  = sarea[pk];
        for (int j = k + 1 + lane; j < cnt; j += 64) {
            if (!alive[j]) continue;
            int pj = list[j];
            float bx1 = sbox[pj * 4 + 0], by1 = sbox[pj * 4 + 1];
            float bx2 = sbox[pj * 4 + 2], by2 = sbox[pj * 4 + 3];
            float iw = fminf(kx2, bx2) - fmaxf(kx1, bx1); iw = fmaxf(iw, 0.0f);
            float ih = fminf(ky2, by2) - fmaxf(ky1, by1); ih = fmaxf(ih, 0.0f);
            float inter = iw * ih;
            float denom = ((ka + sarea[pj]) - inter) + 1e-9f;
            float iou = inter / denom;
            if (iou > 0.5f) alive[j] = 0;
        }
    }
    __syncthreads();
    for (int j = lane; j < cnt; j += 64) keep[list[j]] = alive[j];
}

// ---------------- 5: write outputs (f32, concatenated in return order) ----------------
__global__ void output_kernel(const float* __restrict__ sbox, const float* __restrict__ ssc,
                              const int* __restrict__ scls, const int* __restrict__ keep,
                              float* __restrict__ out) {
    int p = blockIdx.x * blockDim.x + threadIdx.x;
    if (p >= N) return;
    float kf = keep[p] ? 1.0f : 0.0f;
    out[p * 4 + 0] = sbox[p * 4 + 0] * kf;
    out[p * 4 + 1] = sbox[p * 4 + 1] * kf;
    out[p * 4 + 2] = sbox[p * 4 + 2] * kf;
    out[p * 4 + 3] = sbox[p * 4 + 3] * kf;
    out[4 * N + p] = ssc[p] * kf;
    out[5 * N + p] = (float)scls[p];
    out[6 * N + p] = kf;
}

extern "C" void kernel_launch(void* const* d_in, const int* in_sizes, int n_in,
                              void* d_out, int out_size, void* d_ws, size_t ws_size,
                              hipStream_t stream) {
    const float* pred = (const float*)d_in[0];
    char* ws = (char*)d_ws;
    float* fbox  = (float*)(ws + 0);
    float* sbox  = (float*)(ws + 65536);
    float* farea = (float*)(ws + 131072);
    float* sarea = (float*)(ws + 147456);
    float* fsc   = (float*)(ws + 163840);
    float* ssc   = (float*)(ws + 180224);
    int*   fcls  = (int*)(ws + 196608);
    int*   scls  = (int*)(ws + 212992);
    int*   order = (int*)(ws + 229376);
    int*   keep  = (int*)(ws + 245760);
    float* out = (float*)d_out;

    hipLaunchKernelGGL(decode_kernel, dim3(64), dim3(64), 0, stream, pred, fbox, farea, fsc, fcls);
    hipLaunchKernelGGL(sort_kernel, dim3(1), dim3(1024), 0, stream, fsc, order);
    hipLaunchKernelGGL(gather_kernel, dim3(N / 256), dim3(256), 0, stream, order, fbox, farea, fsc, fcls, sbox, sarea, ssc, scls);
    hipLaunchKernelGGL(nms_kernel, dim3(NCLS), dim3(64), 0, stream, sbox, sarea, scls, keep);
    hipLaunchKernelGGL(output_kernel, dim3(N / 256), dim3(256), 0, stream, sbox, ssc, scls, keep, out);
}

// Round 6
// 56.907 us; speedup vs baseline: 2.3765x; 2.3765x over previous
//
#include <hip/hip_runtime.h>

#define N 4096
#define NCH 85
#define NCLS 80
#define CAP 1024

// correctly-rounded f32 exp proxy: compute in f64, round once to f32
__device__ __forceinline__ float ef32(float x) { return (float)exp((double)x); }

// ---------------- 1: decode, 8 lanes per box, bit-faithful f32 numpy emulation ----------------
// lane g in [0,8) owns logits i = 8k+g (k=0..9) == numpy's 8-accumulator pairwise layout.
__global__ __launch_bounds__(256) void decode_kernel(const float* __restrict__ pred,
                                                     float* __restrict__ fbox, float* __restrict__ farea,
                                                     float* __restrict__ fsc, int* __restrict__ fcls) {
    int tid = threadIdx.x;
    int lane = tid & 63;
    int g = tid & 7;
    int b = (blockIdx.x * 256 + tid) >> 3;
    if (b >= N) return;
    const float* p = pred + (size_t)b * NCH;

    float v[10], e[10];
    #pragma unroll
    for (int k = 0; k < 10; ++k) v[k] = p[5 + 8 * k + g];

    // row max (order-independent, exact)
    float m = v[0];
    #pragma unroll
    for (int k = 1; k < 10; ++k) m = fmaxf(m, v[k]);
    #pragma unroll
    for (int off = 1; off <= 4; off <<= 1) m = fmaxf(m, __shfl_xor(m, off));

    // accumulator r[g]: sequential k-ascending adds (numpy per-accumulator order)
    e[0] = ef32(v[0] - m);
    float r = e[0];
    #pragma unroll
    for (int k = 1; k < 10; ++k) { e[k] = ef32(v[k] - m); r += e[k]; }

    // exact pairwise tree ((r0+r1)+(r2+r3))+((r4+r5)+(r6+r7)) — lane g==0 has exact order
    float u = r + __shfl_xor(r, 1);
    float w2 = u + __shfl_xor(u, 2);
    float s = w2 + __shfl_xor(w2, 4);
    s = __shfl(s, lane & ~7);     // broadcast group-base (exact-order) value

    // argmax over pi = fl(e/s), global first-index semantics
    float best = -1.0f; int bi = 127;
    #pragma unroll
    for (int k = 0; k < 10; ++k) {
        float pi = e[k] / s;
        int i = 8 * k + g;
        if (pi > best) { best = pi; bi = i; }
    }
    #pragma unroll
    for (int off = 1; off <= 4; off <<= 1) {
        float ob = __shfl_xor(best, off);
        int   oi = __shfl_xor(bi, off);
        if (ob > best || (ob == best && oi < bi)) { best = ob; bi = oi; }
    }

    if (g == 0) {
        float conf = 1.0f / (1.0f + ef32(-p[4]));
        fsc[b] = conf * best;
        fcls[b] = bi;
        float x = p[0], y = p[1], w = p[2], h = p[3];
        float x1 = x - 0.5f * w, y1 = y - 0.5f * h;
        float x2 = x + 0.5f * w, y2 = y + 0.5f * h;
        fbox[4 * b + 0] = x1; fbox[4 * b + 1] = y1;
        fbox[4 * b + 2] = x2; fbox[4 * b + 3] = y2;
        farea[b] = fmaxf(x2 - x1, 0.0f) * fmaxf(y2 - y1, 0.0f);
    }
}

// ---------------- 2: rank-by-counting + fused scatter-gather ----------------
// rank_i = #{j: bits_j > bits_i} + #{j<i: bits_j == bits_i}  == stable descending order.
// One wave per box (4 boxes/block); scores staged in LDS; writes sorted records directly.
__global__ __launch_bounds__(256) void rank_kernel(const float* __restrict__ fsc,
                                                   const float* __restrict__ fbox,
                                                   const float* __restrict__ farea,
                                                   const int* __restrict__ fcls,
                                                   float* __restrict__ sbox, float* __restrict__ sarea,
                                                   float* __restrict__ ssc, int* __restrict__ scls) {
    __shared__ unsigned int bits[N];
    int tid = threadIdx.x;
    #pragma unroll
    for (int i = 0; i < 16; ++i) bits[tid + i * 256] = __float_as_uint(fsc[tid + i * 256]);
    __syncthreads();

    int wave = tid >> 6, lane = tid & 63;
    int b = blockIdx.x * 4 + wave;
    unsigned int mb = bits[b];
    int cnt = 0;
    for (int it = 0; it < 64; ++it) {
        int j = it * 64 + lane;
        unsigned int bj = bits[j];
        if (bj > mb) cnt++;
        if (bj == mb && j < b) cnt++;
    }
    #pragma unroll
    for (int off = 32; off; off >>= 1) cnt += __shfl_xor(cnt, off);

    if (lane == 0) {
        int rk = cnt;
        sbox[rk * 4 + 0] = fbox[b * 4 + 0];
        sbox[rk * 4 + 1] = fbox[b * 4 + 1];
        sbox[rk * 4 + 2] = fbox[b * 4 + 2];
        sbox[rk * 4 + 3] = fbox[b * 4 + 3];
        sarea[rk] = farea[b];
        ssc[rk]   = fsc[b];
        scls[rk]  = fcls[b];
    }
}

// ---------------- 3: np-argsort tie-order fixup (proven rounds 1-4) ----------------
// np.argsort(-scores) orders the 1st adjacent bitwise-tie pair index-ascending and the
// 2nd index-descending; stable order is index-ascending everywhere -> swap pair 2's records.
__global__ __launch_bounds__(256) void fixup_kernel(float* __restrict__ sbox, float* __restrict__ sarea,
                                                    const float* __restrict__ ssc, int* __restrict__ scls) {
    __shared__ int tpos[32];
    __shared__ int tn;
    if (threadIdx.x == 0) tn = 0;
    __syncthreads();
    for (int p = threadIdx.x; p < N - 1; p += 256) {
        if (__float_as_uint(ssc[p]) == __float_as_uint(ssc[p + 1])) {
            int i = atomicAdd(&tn, 1);
            if (i < 32) tpos[i] = p;
        }
    }
    __syncthreads();
    if (threadIdx.x == 0 && tn >= 2) {
        int m = tn < 32 ? tn : 32;
        int first = 1 << 30, second = 1 << 30;
        for (int i = 0; i < m; ++i) {
            int v = tpos[i];
            if (v < first) { second = first; first = v; }
            else if (v < second) second = v;
        }
        int p = second;   // scores bitwise equal -> only box/area/class swap
        #pragma unroll
        for (int q = 0; q < 4; ++q) {
            float a = sbox[p * 4 + q]; sbox[p * 4 + q] = sbox[(p + 1) * 4 + q]; sbox[(p + 1) * 4 + q] = a;
        }
        float a = sarea[p]; sarea[p] = sarea[p + 1]; sarea[p + 1] = a;
        int ci = scls[p]; scls[p] = scls[p + 1]; scls[p + 1] = ci;
    }
}

// ---------------- 4: per-class greedy NMS, register-prefetch + LDS-staged coords ----------------
__global__ __launch_bounds__(64) void nms_kernel(const float* __restrict__ sbox,
                                                 const float* __restrict__ sarea,
                                                 const int* __restrict__ scls,
                                                 int* __restrict__ keep) {
    __shared__ float lx1[CAP], ly1[CAP], lx2[CAP], ly2[CAP], lar[CAP];
    __shared__ unsigned short lpos[CAP];
    __shared__ unsigned char alive[CAP];
    int c = blockIdx.x, lane = threadIdx.x;

    // prefetch this lane's 64 class values (64 independent coalesced loads in flight)
    int myc[64];
    #pragma unroll
    for (int t = 0; t < 64; ++t) myc[t] = scls[t * 64 + lane];

    int cnt = 0;
    for (int t = 0; t < 64; ++t) {
        bool is_c = (myc[t] == c);
        unsigned long long bal = __ballot(is_c);
        int off = __popcll(bal & ((1ull << lane) - 1ull));
        if (is_c) {
            int slot = cnt + off;
            if (slot < CAP) {
                int pos = t * 64 + lane;
                float4 bx = *(const float4*)&sbox[pos * 4];
                lx1[slot] = bx.x; ly1[slot] = bx.y; lx2[slot] = bx.z; ly2[slot] = bx.w;
                lar[slot] = sarea[pos];
                lpos[slot] = (unsigned short)pos;
            }
        }
        cnt += __popcll(bal);
    }
    if (cnt > CAP) cnt = CAP;   // statistically impossible guard (E[cnt]=51)
    for (int j = lane; j < cnt; j += 64) alive[j] = 1;
    __syncthreads();

    for (int k = 0; k < cnt; ++k) {
        __syncthreads();
        if (!alive[k]) continue;   // uniform LDS read
        float kx1 = lx1[k], ky1 = ly1[k], kx2 = lx2[k], ky2 = ly2[k], ka = lar[k];
        for (int j = k + 1 + lane; j < cnt; j += 64) {
            if (!alive[j]) continue;
            float iw = fminf(kx2, lx2[j]) - fmaxf(kx1, lx1[j]); iw = fmaxf(iw, 0.0f);
            float ih = fminf(ky2, ly2[j]) - fmaxf(ky1, ly1[j]); ih = fmaxf(ih, 0.0f);
            float inter = iw * ih;
            float denom = ((ka + lar[j]) - inter) + 1e-9f;   // numpy left-to-right order
            if (inter / denom > 0.5f) alive[j] = 0;
        }
    }
    __syncthreads();
    for (int j = lane; j < cnt; j += 64) keep[lpos[j]] = alive[j];
}

// ---------------- 5: write outputs (f32, concatenated in return order) ----------------
__global__ __launch_bounds__(256) void output_kernel(const float* __restrict__ sbox, const float* __restrict__ ssc,
                                                     const int* __restrict__ scls, const int* __restrict__ keep,
                                                     float* __restrict__ out) {
    int p = blockIdx.x * blockDim.x + threadIdx.x;
    if (p >= N) return;
    float kf = keep[p] ? 1.0f : 0.0f;
    out[p * 4 + 0] = sbox[p * 4 + 0] * kf;
    out[p * 4 + 1] = sbox[p * 4 + 1] * kf;
    out[p * 4 + 2] = sbox[p * 4 + 2] * kf;
    out[p * 4 + 3] = sbox[p * 4 + 3] * kf;
    out[4 * N + p] = ssc[p] * kf;
    out[5 * N + p] = (float)scls[p];
    out[6 * N + p] = kf;
}

extern "C" void kernel_launch(void* const* d_in, const int* in_sizes, int n_in,
                              void* d_out, int out_size, void* d_ws, size_t ws_size,
                              hipStream_t stream) {
    const float* pred = (const float*)d_in[0];
    char* ws = (char*)d_ws;
    float* fbox  = (float*)(ws + 0);        // 65536 B
    float* sbox  = (float*)(ws + 65536);    // 65536 B
    float* farea = (float*)(ws + 131072);   // 16384 B
    float* sarea = (float*)(ws + 147456);   // 16384 B
    float* fsc   = (float*)(ws + 163840);   // 16384 B
    float* ssc   = (float*)(ws + 180224);   // 16384 B
    int*   fcls  = (int*)(ws + 196608);     // 16384 B
    int*   scls  = (int*)(ws + 212992);     // 16384 B
    int*   keep  = (int*)(ws + 229376);     // 16384 B
    float* out = (float*)d_out;

    hipLaunchKernelGGL(decode_kernel, dim3(128), dim3(256), 0, stream, pred, fbox, farea, fsc, fcls);
    hipLaunchKernelGGL(rank_kernel, dim3(N / 4), dim3(256), 0, stream, fsc, fbox, farea, fcls, sbox, sarea, ssc, scls);
    hipLaunchKernelGGL(fixup_kernel, dim3(1), dim3(256), 0, stream, sbox, sarea, ssc, scls);
    hipLaunchKernelGGL(nms_kernel, dim3(NCLS), dim3(64), 0, stream, sbox, sarea, scls, keep);
    hipLaunchKernelGGL(output_kernel, dim3(16), dim3(256), 0, stream, sbox, ssc, scls, keep, out);
}